// Round 7
// baseline (46.294 us; speedup 1.0000x reference)
//
#include <hip/hip_runtime.h>
#include <hip/hip_cooperative_groups.h>
#include <math.h>

#define B_ 8
#define Q_ 4096
#define N_ 128
#define EPS_ 1e-5f

typedef unsigned int u32;

__device__ __forceinline__ float wave_sum64(float x) {
    #pragma unroll
    for (int o = 32; o > 0; o >>= 1) x += __shfl_xor(x, o, 64);
    return x;
}

// ---------------------------------------------------------------------------
// Single cooperative kernel: 256 blocks x 1024 threads.
// Phase 1 (all blocks): geometry (redundant per batch-slice), density for 4
// sample points, CE partials for 128 queries, MSE partial -> part[] in ws.
// grid.sync(). Phase 2 (block 0): fixed-order combine + den-rank + 3 losses.
// ---------------------------------------------------------------------------
__global__ __launch_bounds__(1024) void fused_kernel(
    const float* __restrict__ pred_logits,  // (B,Q,2)
    const float* __restrict__ pred_points,  // (B,Q,2)
    const float* __restrict__ tgt_points,   // (B,N,2)
    const float* __restrict__ split_map,    // (B,Q)
    const int*   __restrict__ src_idx,      // (B,N)
    const int*   __restrict__ labels,       // (B,N)
    const float4* __restrict__ prob,
    const float4* __restrict__ prob_est,
    const float* __restrict__ den,          // (B,)
    float4* __restrict__ part,              // (256*2): [ce4], [p0,p1,p2,mse]
    float*  __restrict__ out)               // (3,)
{
    const int g = blockIdx.x;
    const int b = g >> 5;
    const int s = g & 31;
    const int t = threadIdx.x;

    __shared__ u32    bits[Q_ / 32];   // 128 words
    __shared__ int    spk[N_];         // (ipx<<8)|ipy
    __shared__ float  sdi[N_];
    __shared__ float4 sgeo[N_];        // px,py,half,2s^2
    __shared__ float  ssmp[4][3];      // gx,gy,spl per local sample point
    __shared__ float  dcor[16];        // 4 points x 4 corners
    __shared__ float  ptvs[4][3];
    __shared__ float  wred[16 * 5];

    // ---- entry: issue ALL global loads ----
    float4 mseA, mseB;
    if (t < 512) {
        int i = g * 512 + t;
        mseA = prob[i];
        mseB = prob_est[i];
    }
    float l0 = 0.f, l1 = 0.f, smq = 0.f;
    if (t < 128) {
        int q = s * 128 + t;
        l0  = pred_logits[(b * Q_ + q) * 2 + 0];
        l1  = pred_logits[(b * Q_ + q) * 2 + 1];
        smq = split_map[b * Q_ + q];
    }
    float2 tp = make_float2(0.f, 0.f);
    int srcp = 0, lab = 0;
    if (t < N_) {
        tp   = ((const float2*)tgt_points)[b * N_ + t];
        srcp = src_idx[b * N_ + t];
        lab  = labels[b * N_ + t];
        bits[t] = 0u;
    }
    float sgx = 0.f, sgy = 0.f, sspl = 0.f;
    if (t < 4) {   // 2-deep dependent gather chain for this block's 4 points
        int srcn = src_idx[b * N_ + s * 4 + t];
        float sx = pred_points[(b * Q_ + srcn) * 2 + 0];
        float sy = pred_points[(b * Q_ + srcn) * 2 + 1];
        sspl = split_map[b * Q_ + srcn];
        sgx = fminf(fmaxf(sx * 256.f, 0.f), 255.f);
        sgy = fminf(fmaxf(sy * 256.f, 0.f), 255.f);
    }

    if (t < N_) {
        float px = rintf((tp.x / 256.f) * 256.f);   // round-half-even
        float py = rintf((tp.y / 256.f) * 256.f);
        px = fminf(fmaxf(px, 0.f), 255.f);
        py = fminf(fmaxf(py, 0.f), 255.f);
        spk[t] = (((int)px) << 8) | ((int)py);
    }
    if (t < 4) { ssmp[t][0] = sgx; ssmp[t][1] = sgy; ssmp[t][2] = sspl; }
    __syncthreads();   // A: bits zeroed, spk ready, ssmp ready

    if (t < N_ && lab != 0) atomicOr(&bits[srcp >> 5], 1u << (srcp & 31));

    // ---- NN top-4: 8 lanes per point, integer keys (d2<<7)|j ----
    {
        const int p = t >> 3;
        const int r = t & 7;
        int mypk = spk[p];
        int myx = mypk >> 8, myy = mypk & 255;
        u32 s0 = 0x7fffffffu, s1 = 0x7fffffffu, s2 = 0x7fffffffu, s3 = 0x7fffffffu;
        #pragma unroll
        for (int jj = 0; jj < 16; ++jj) {
            int j  = jj * 8 + r;
            int pk = spk[j];
            int dx = (pk >> 8) - myx;
            int dy = (pk & 255) - myy;
            u32 u = ((u32)(dx * dx + dy * dy) << 7) | (u32)j;
            u32 m0 = min(s0, u); u = max(s0, u); s0 = m0;
            u32 m1 = min(s1, u); u = max(s1, u); s1 = m1;
            u32 m2 = min(s2, u); u = max(s2, u); s2 = m2;
            s3 = min(s3, u);
        }
        // merge sorted 4-lists across the 8-lane group (keep-low bitonic)
        #pragma unroll
        for (int m = 1; m <= 4; m <<= 1) {
            u32 q0 = (u32)__shfl_xor((int)s0, m, 64);
            u32 q1 = (u32)__shfl_xor((int)s1, m, 64);
            u32 q2 = (u32)__shfl_xor((int)s2, m, 64);
            u32 q3 = (u32)__shfl_xor((int)s3, m, 64);
            u32 l0_ = min(s0, q3), l1_ = min(s1, q2), l2_ = min(s2, q1), l3_ = min(s3, q0);
            u32 a0 = min(l0_, l2_), a2 = max(l0_, l2_);
            u32 a1 = min(l1_, l3_), a3 = max(l1_, l3_);
            s0 = min(a0, a1); s1 = max(a0, a1);
            s2 = min(a2, a3); s3 = max(a2, a3);
        }
        float di = sqrtf((float)(s1 >> 7));
        if (r == 0) sdi[p] = di;
        __syncthreads();   // C: sdi ready (also makes atomicOr results visible)
        if (r == 0) {
            int nb1 = (int)(s1 & 127u), nb2 = (int)(s2 & 127u), nb3 = (int)(s3 & 127u);
            float dmean = ((sdi[nb1] + sdi[nb2]) + sdi[nb3]) / 3.0f;
            float d     = fminf(di, dmean);
            float sigma = fmaxf(0.4f * d, 1.0f);
            int ks = (int)(6.0f * sigma);
            if ((ks & 1) == 0) ks += 1;
            sgeo[p] = make_float4((float)(mypk >> 8), (float)(mypk & 255),
                                  (float)(ks / 2), 2.0f * sigma * sigma);
        }
    }
    __syncthreads();   // D: sgeo ready

    // ---- density: wave w handles (point p_loc = w>>2, corner c = w&3) ----
    {
        const int w     = t >> 6;
        const int lw    = t & 63;
        const int p_loc = w >> 2;
        const int c     = w & 3;
        float gx = ssmp[p_loc][0], gy = ssmp[p_loc][1];
        int x0 = (int)floorf(gx), y0 = (int)floorf(gy);
        int x1 = min(x0 + 1, 255), y1 = min(y0 + 1, 255);
        float cx = (float)((c & 1) ? x1 : x0);
        float cy = (float)((c & 2) ? y1 : y0);
        float lmax = 0.f;
        #pragma unroll
        for (int k = 0; k < 2; ++k) {
            float4 G = sgeo[lw + 64 * k];
            float dy = cy - G.y, dx = cx - G.x;
            if (fabsf(dy) <= G.z && fabsf(dx) <= G.z)
                lmax = fmaxf(lmax, expf(-(dy * dy + dx * dx) / G.w));
        }
        #pragma unroll
        for (int o = 32; o > 0; o >>= 1)
            lmax = fmaxf(lmax, __shfl_xor(lmax, o, 64));
        if (lw == 0) dcor[p_loc * 4 + c] = lmax;
    }
    __syncthreads();   // E: dcor ready

    if (t < 4) {   // bilinear + per-point loss values (LDS only)
        float gx = ssmp[t][0], gy = ssmp[t][1], spl = ssmp[t][2];
        int x0 = (int)floorf(gx), y0 = (int)floorf(gy);
        float fx = gx - (float)x0, fy = gy - (float)y0;
        float d00 = dcor[t * 4 + 0], d01 = dcor[t * 4 + 1];
        float d10 = dcor[t * 4 + 2], d11 = dcor[t * 4 + 3];
        float pv = (1.f - fy) * (1.f - fx) * d00 + (1.f - fy) * fx * d01
                 + fy * (1.f - fx) * d10 + fy * fx * d11;
        float lr   = 0.05f * (1.0f - pv);
        float divf = (spl > 0.5f) ? 1.0f : 0.0f;
        ptvs[t][0] = 2.0f * lr * divf;
        ptvs[t][1] = 2.0f * lr * (1.0f - divf);
        ptvs[t][2] = 1.0f - divf;
    }

    // ---- CE partials (bits visible since barrier C) ----
    float s_dn = 0.f, s_dd = 0.f, s_nn = 0.f, s_nd = 0.f;
    if (t < 128) {
        int q = s * 128 + t;
        int tc = (bits[q >> 5] >> (q & 31)) & 1;
        float mx  = fmaxf(l0, l1);
        float lse = mx + logf(expf(l0 - mx) + expf(l1 - mx));
        float rce = lse - (tc ? l1 : l0);
        float w   = tc ? 1.0f : 0.5f;
        float dmf = (smq > 0.5f) ? 1.0f : 0.0f;
        s_dn = rce * w * dmf;
        s_dd = w * dmf;
        s_nn = rce * w * (1.0f - dmf);
        s_nd = w * (1.0f - dmf);
    }

    // ---- MSE partial ----
    float msum = 0.f;
    if (t < 512) {
        float d;
        d = mseA.x - mseB.x; msum += d * d;
        d = mseA.y - mseB.y; msum += d * d;
        d = mseA.z - mseB.z; msum += d * d;
        d = mseA.w - mseB.w; msum += d * d;
    }

    // ---- block reduction (fixed order -> deterministic) ----
    float r0 = wave_sum64(s_dn), r1 = wave_sum64(s_dd);
    float r2 = wave_sum64(s_nn), r3 = wave_sum64(s_nd);
    float r4 = wave_sum64(msum);
    const int wid = t >> 6;
    if ((t & 63) == 0) {
        wred[wid * 5 + 0] = r0; wred[wid * 5 + 1] = r1;
        wred[wid * 5 + 2] = r2; wred[wid * 5 + 3] = r3;
        wred[wid * 5 + 4] = r4;
    }
    __syncthreads();   // F
    if (t == 0) {
        float a0 = 0.f, a1 = 0.f, a2 = 0.f, a3 = 0.f, a4 = 0.f;
        for (int wv = 0; wv < 16; ++wv) {
            a0 += wred[wv * 5 + 0]; a1 += wred[wv * 5 + 1];
            a2 += wred[wv * 5 + 2]; a3 += wred[wv * 5 + 3];
            a4 += wred[wv * 5 + 4];
        }
        float p0 = ptvs[0][0] + ptvs[1][0] + ptvs[2][0] + ptvs[3][0];
        float p1 = ptvs[0][1] + ptvs[1][1] + ptvs[2][1] + ptvs[3][1];
        float p2 = ptvs[0][2] + ptvs[1][2] + ptvs[2][2] + ptvs[3][2];
        part[g * 2 + 0] = make_float4(a0, a1, a2, a3);
        part[g * 2 + 1] = make_float4(p0, p1, p2, a4);
    }

    // ---- grid-wide barrier ----
    cooperative_groups::this_grid().sync();

    // ---- Phase 2: block 0, first wave: final combine ----
    if (g != 0 || t >= 64) return;
    {
        const int bb = t >> 3;   // batch
        const int c  = t & 7;    // chunk of 4 slices
        __shared__ float4 bce[B_], bpt[B_];

        float4 A = make_float4(0.f, 0.f, 0.f, 0.f);
        float4 P = make_float4(0.f, 0.f, 0.f, 0.f);
        for (int k = 0; k < 4; ++k) {           // fixed-order sequential
            int gg = bb * 32 + c * 4 + k;
            float4 a = part[gg * 2 + 0], p = part[gg * 2 + 1];
            A.x += a.x; A.y += a.y; A.z += a.z; A.w += a.w;
            P.x += p.x; P.y += p.y; P.z += p.z; P.w += p.w;
        }
        #pragma unroll
        for (int o = 1; o <= 4; o <<= 1) {      // fixed-order tree over 8 chunks
            A.x += __shfl_xor(A.x, o, 64); A.y += __shfl_xor(A.y, o, 64);
            A.z += __shfl_xor(A.z, o, 64); A.w += __shfl_xor(A.w, o, 64);
            P.x += __shfl_xor(P.x, o, 64); P.y += __shfl_xor(P.y, o, 64);
            P.z += __shfl_xor(P.z, o, 64); P.w += __shfl_xor(P.w, o, 64);
        }
        if (c == 0) { bce[bb] = A; bpt[bb] = P; }
        __builtin_amdgcn_s_barrier();   // only wave 0 alive in block 0

        if (t == 0) {
            float dn[B_];
            for (int i = 0; i < B_; ++i) dn[i] = den[i];

            float mse = 0.f;
            float num_sp = 0.f, den_sp = 0.f, num_ds = 0.f, den_ds = 0.f;
            float num_nd = 0.f, den_nd = 0.f;
            float p_sp = 0.f, p_ds = 0.f, p_nd = 0.f, cnt_nd = 0.f;
            for (int b2 = 0; b2 < B_; ++b2) {
                int rank = 0;
                for (int j = 0; j < B_; ++j)
                    rank += ((dn[j] < dn[b2]) || (dn[j] == dn[b2] && j < b2)) ? 1 : 0;
                float sp  = (rank >= B_ / 2) ? 1.0f : 0.0f;
                float dsv = 1.0f - sp;
                float4 A2 = bce[b2], P2 = bpt[b2];
                mse += P2.w;
                num_sp += sp  * A2.x;  den_sp += sp  * A2.y;
                num_ds += dsv * A2.x;  den_ds += dsv * A2.y;
                num_nd += A2.z;        den_nd += A2.w;
                p_sp   += sp  * P2.x;  p_ds   += dsv * P2.x;
                p_nd   += P2.y;        cnt_nd += P2.z;
            }
            float loss_ce = num_sp / (den_sp + EPS_)
                          + num_ds / (den_ds + EPS_)
                          + num_nd / (den_nd + EPS_);
            float half_cnt = (float)(N_ * (B_ / 2));   // sp/ds point counts = 512
            float loss_points = p_sp / (half_cnt + EPS_)
                              + p_ds / (half_cnt + EPS_)
                              + p_nd / (cnt_nd + EPS_);
            out[0] = loss_ce;
            out[1] = loss_points;
            out[2] = mse / (float)(B_ * 256 * 256);
        }
    }
}

extern "C" void kernel_launch(void* const* d_in, const int* in_sizes, int n_in,
                              void* d_out, int out_size, void* d_ws, size_t ws_size,
                              hipStream_t stream) {
    const float* pred_logits = (const float*)d_in[0];
    const float* pred_points = (const float*)d_in[1];
    const float* tgt_points  = (const float*)d_in[2];
    const float* split_map   = (const float*)d_in[3];
    const float* den         = (const float*)d_in[4];
    const float4* prob       = (const float4*)d_in[5];
    const float4* prob_est   = (const float4*)d_in[6];
    const int*   src_idx     = (const int*)d_in[7];
    const int*   labels      = (const int*)d_in[8];
    float* out = (float*)d_out;

    float4* part = (float4*)d_ws;   // 512 float4 = 8 KB

    void* args[] = {
        (void*)&pred_logits, (void*)&pred_points, (void*)&tgt_points,
        (void*)&split_map, (void*)&src_idx, (void*)&labels,
        (void*)&prob, (void*)&prob_est, (void*)&den,
        (void*)&part, (void*)&out
    };
    hipLaunchCooperativeKernel((const void*)fused_kernel, dim3(256), dim3(1024),
                               args, 0, stream);
}

// Round 8
// 14.783 us; speedup vs baseline: 3.1315x; 3.1315x over previous
//
#include <hip/hip_runtime.h>
#include <math.h>

#define B_ 8
#define Q_ 4096
#define N_ 128
#define EPS_ 1e-5f

typedef unsigned int u32;

__device__ __forceinline__ float wave_sum64(float x) {
    #pragma unroll
    for (int o = 32; o > 0; o >>= 1) x += __shfl_xor(x, o, 64);
    return x;
}

// ---------------------------------------------------------------------------
// Main kernel: 256 independent blocks x 1024 threads.
// Block g: batch b = g>>5, slice s = g&31.
//  - builds batch geometry (pixel coords, top-4 NN, sigma) REDUNDANTLY
//  - density + point-loss for its 4 sample points (1 wave per point-corner)
//  - CE partials for its 128 queries (via LDS target-class bitmap)
//  - MSE partial over its 1/256 slice of the prob maps
// Writes 2 float4 partials to ws. No cross-block communication.
// (Round-4/7 lesson: cross-block fusion via atomics or coop grid-sync costs
//  30+ µs on 8 non-coherent XCDs — the 2-launch structure is the floor.)
// ---------------------------------------------------------------------------
__global__ __launch_bounds__(1024) void main_kernel(
    const float* __restrict__ pred_logits,  // (B,Q,2)
    const float* __restrict__ pred_points,  // (B,Q,2)
    const float* __restrict__ tgt_points,   // (B,N,2)
    const float* __restrict__ split_map,    // (B,Q)
    const int*   __restrict__ src_idx,      // (B,N)
    const int*   __restrict__ labels,       // (B,N)
    const float4* __restrict__ prob,
    const float4* __restrict__ prob_est,
    float4* __restrict__ part)              // (256*2): [ce4], [p0,p1,p2,mse]
{
    const int g = blockIdx.x;
    const int b = g >> 5;
    const int s = g & 31;
    const int t = threadIdx.x;

    __shared__ u32    bits[Q_ / 32];   // 128 words
    __shared__ int    spk[N_];         // (ipx<<8)|ipy
    __shared__ float  sdi[N_];
    __shared__ float4 sgeo[N_];        // px,py,half,2s^2
    __shared__ float  dcor[16];        // 4 points x 4 corners
    __shared__ float  ptvs[4][3];
    __shared__ float  wred[16 * 5];

    // ---- early global loads (latency hides under geometry phases) ----
    float4 mseA, mseB;
    if (t < 512) {
        int i = g * 512 + t;
        mseA = prob[i];
        mseB = prob_est[i];
    }
    float l0 = 0.f, l1 = 0.f, smq = 0.f;
    if (t < 128) {
        int q = s * 128 + t;
        l0  = pred_logits[(b * Q_ + q) * 2 + 0];
        l1  = pred_logits[(b * Q_ + q) * 2 + 1];
        smq = split_map[b * Q_ + q];
    }
    float2 tp = make_float2(0.f, 0.f);
    int srcp = 0, lab = 0;
    if (t < N_) {
        tp   = ((const float2*)tgt_points)[b * N_ + t];
        srcp = src_idx[b * N_ + t];
        lab  = labels[b * N_ + t];
        bits[t] = 0u;
    }
    __syncthreads();   // A: bits zeroed

    if (t < N_) {
        float px = rintf((tp.x / 256.f) * 256.f);   // round-half-even
        float py = rintf((tp.y / 256.f) * 256.f);
        px = fminf(fmaxf(px, 0.f), 255.f);
        py = fminf(fmaxf(py, 0.f), 255.f);
        spk[t] = (((int)px) << 8) | ((int)py);
        if (lab != 0) atomicOr(&bits[srcp >> 5], 1u << (srcp & 31));
    }
    __syncthreads();   // B: spk + bits ready

    // ---- NN top-4: 8 lanes per point, integer keys (d2<<7)|j ----
    {
        const int p = t >> 3;
        const int r = t & 7;
        int mypk = spk[p];
        int myx = mypk >> 8, myy = mypk & 255;
        u32 s0 = 0x7fffffffu, s1 = 0x7fffffffu, s2 = 0x7fffffffu, s3 = 0x7fffffffu;
        #pragma unroll
        for (int jj = 0; jj < 16; ++jj) {
            int j  = jj * 8 + r;               // same-addr across 8-groups: broadcast
            int pk = spk[j];
            int dx = (pk >> 8) - myx;
            int dy = (pk & 255) - myy;
            u32 u = ((u32)(dx * dx + dy * dy) << 7) | (u32)j;
            u32 m0 = min(s0, u); u = max(s0, u); s0 = m0;
            u32 m1 = min(s1, u); u = max(s1, u); s1 = m1;
            u32 m2 = min(s2, u); u = max(s2, u); s2 = m2;
            s3 = min(s3, u);
        }
        // merge sorted 4-lists across the 8-lane group (keep-low bitonic)
        #pragma unroll
        for (int m = 1; m <= 4; m <<= 1) {
            u32 q0 = (u32)__shfl_xor((int)s0, m, 64);
            u32 q1 = (u32)__shfl_xor((int)s1, m, 64);
            u32 q2 = (u32)__shfl_xor((int)s2, m, 64);
            u32 q3 = (u32)__shfl_xor((int)s3, m, 64);
            u32 l0_ = min(s0, q3), l1_ = min(s1, q2), l2_ = min(s2, q1), l3_ = min(s3, q0);
            u32 a0 = min(l0_, l2_), a2 = max(l0_, l2_);
            u32 a1 = min(l1_, l3_), a3 = max(l1_, l3_);
            s0 = min(a0, a1); s1 = max(a0, a1);
            s2 = min(a2, a3); s3 = max(a2, a3);
        }
        float di = sqrtf((float)(s1 >> 7));
        if (r == 0) sdi[p] = di;
        __syncthreads();   // C: sdi ready
        if (r == 0) {
            int nb1 = (int)(s1 & 127u), nb2 = (int)(s2 & 127u), nb3 = (int)(s3 & 127u);
            float dmean = ((sdi[nb1] + sdi[nb2]) + sdi[nb3]) / 3.0f;
            float d     = fminf(di, dmean);
            float sigma = fmaxf(0.4f * d, 1.0f);
            int ks = (int)(6.0f * sigma);
            if ((ks & 1) == 0) ks += 1;
            sgeo[p] = make_float4((float)(mypk >> 8), (float)(mypk & 255),
                                  (float)(ks / 2), 2.0f * sigma * sigma);
        }
    }
    __syncthreads();   // D: sgeo ready

    // ---- density: wave w handles (point p_loc = w>>2, corner c = w&3) ----
    {
        const int w     = t >> 6;
        const int lw    = t & 63;
        const int p_loc = w >> 2;
        const int c     = w & 3;
        const int n     = s * 4 + p_loc;
        int   srcn = src_idx[b * N_ + n];
        float sx = pred_points[(b * Q_ + srcn) * 2 + 0];
        float sy = pred_points[(b * Q_ + srcn) * 2 + 1];
        float gx = fminf(fmaxf(sx * 256.f, 0.f), 255.f);
        float gy = fminf(fmaxf(sy * 256.f, 0.f), 255.f);
        int x0 = (int)floorf(gx), y0 = (int)floorf(gy);
        int x1 = min(x0 + 1, 255), y1 = min(y0 + 1, 255);
        float cx = (float)((c & 1) ? x1 : x0);
        float cy = (float)((c & 2) ? y1 : y0);
        float lmax = 0.f;
        #pragma unroll
        for (int k = 0; k < 2; ++k) {
            float4 G = sgeo[lw + 64 * k];
            float dy = cy - G.y, dx = cx - G.x;
            if (fabsf(dy) <= G.z && fabsf(dx) <= G.z)
                lmax = fmaxf(lmax, expf(-(dy * dy + dx * dx) / G.w));
        }
        #pragma unroll
        for (int o = 32; o > 0; o >>= 1)
            lmax = fmaxf(lmax, __shfl_xor(lmax, o, 64));
        if (lw == 0) dcor[p_loc * 4 + c] = lmax;
    }
    __syncthreads();   // E: dcor ready

    if (t < 4) {   // bilinear + per-point loss values
        const int n = s * 4 + t;
        int   srcn = src_idx[b * N_ + n];
        float sx  = pred_points[(b * Q_ + srcn) * 2 + 0];
        float sy  = pred_points[(b * Q_ + srcn) * 2 + 1];
        float spl = split_map[b * Q_ + srcn];
        float gx = fminf(fmaxf(sx * 256.f, 0.f), 255.f);
        float gy = fminf(fmaxf(sy * 256.f, 0.f), 255.f);
        int x0 = (int)floorf(gx), y0 = (int)floorf(gy);
        float fx = gx - (float)x0, fy = gy - (float)y0;
        float d00 = dcor[t * 4 + 0], d01 = dcor[t * 4 + 1];
        float d10 = dcor[t * 4 + 2], d11 = dcor[t * 4 + 3];
        float pv = (1.f - fy) * (1.f - fx) * d00 + (1.f - fy) * fx * d01
                 + fy * (1.f - fx) * d10 + fy * fx * d11;
        float lr   = 0.05f * (1.0f - pv);
        float divf = (spl > 0.5f) ? 1.0f : 0.0f;
        ptvs[t][0] = 2.0f * lr * divf;
        ptvs[t][1] = 2.0f * lr * (1.0f - divf);
        ptvs[t][2] = 1.0f - divf;
    }

    // ---- CE partials (bits ready since barrier B) ----
    float s_dn = 0.f, s_dd = 0.f, s_nn = 0.f, s_nd = 0.f;
    if (t < 128) {
        int q = s * 128 + t;
        int tc = (bits[q >> 5] >> (q & 31)) & 1;
        float mx  = fmaxf(l0, l1);
        float lse = mx + logf(expf(l0 - mx) + expf(l1 - mx));
        float rce = lse - (tc ? l1 : l0);
        float w   = tc ? 1.0f : 0.5f;
        float dmf = (smq > 0.5f) ? 1.0f : 0.0f;
        s_dn = rce * w * dmf;
        s_dd = w * dmf;
        s_nn = rce * w * (1.0f - dmf);
        s_nd = w * (1.0f - dmf);
    }

    // ---- MSE partial ----
    float msum = 0.f;
    if (t < 512) {
        float d;
        d = mseA.x - mseB.x; msum += d * d;
        d = mseA.y - mseB.y; msum += d * d;
        d = mseA.z - mseB.z; msum += d * d;
        d = mseA.w - mseB.w; msum += d * d;
    }

    // ---- block reduction (fixed order -> deterministic) ----
    float r0 = wave_sum64(s_dn), r1 = wave_sum64(s_dd);
    float r2 = wave_sum64(s_nn), r3 = wave_sum64(s_nd);
    float r4 = wave_sum64(msum);
    const int wid = t >> 6;
    if ((t & 63) == 0) {
        wred[wid * 5 + 0] = r0; wred[wid * 5 + 1] = r1;
        wred[wid * 5 + 2] = r2; wred[wid * 5 + 3] = r3;
        wred[wid * 5 + 4] = r4;
    }
    __syncthreads();   // F
    if (t == 0) {
        float a0 = 0.f, a1 = 0.f, a2 = 0.f, a3 = 0.f, a4 = 0.f;
        for (int wv = 0; wv < 16; ++wv) {
            a0 += wred[wv * 5 + 0]; a1 += wred[wv * 5 + 1];
            a2 += wred[wv * 5 + 2]; a3 += wred[wv * 5 + 3];
            a4 += wred[wv * 5 + 4];
        }
        float p0 = ptvs[0][0] + ptvs[1][0] + ptvs[2][0] + ptvs[3][0];
        float p1 = ptvs[0][1] + ptvs[1][1] + ptvs[2][1] + ptvs[3][1];
        float p2 = ptvs[0][2] + ptvs[1][2] + ptvs[2][2] + ptvs[3][2];
        part[g * 2 + 0] = make_float4(a0, a1, a2, a3);
        part[g * 2 + 1] = make_float4(p0, p1, p2, a4);
    }
}

// ---------------------------------------------------------------------------
// Final: 1 block x 64 threads. Fixed-order reduce of 256 slice-partials,
// den-rank split, three losses.
// ---------------------------------------------------------------------------
__global__ __launch_bounds__(64) void final_kernel(
    const float*  __restrict__ den,    // (B,)
    const float4* __restrict__ part,   // (256*2)
    float* __restrict__ out)           // (3,)
{
    const int t = threadIdx.x;
    const int bb = t >> 3;   // batch
    const int c  = t & 7;    // chunk of 4 slices
    __shared__ float4 bce[B_], bpt[B_];

    float4 A = make_float4(0.f, 0.f, 0.f, 0.f);
    float4 P = make_float4(0.f, 0.f, 0.f, 0.f);
    for (int k = 0; k < 4; ++k) {           // fixed-order sequential
        int g = bb * 32 + c * 4 + k;
        float4 a = part[g * 2 + 0], p = part[g * 2 + 1];
        A.x += a.x; A.y += a.y; A.z += a.z; A.w += a.w;
        P.x += p.x; P.y += p.y; P.z += p.z; P.w += p.w;
    }
    #pragma unroll
    for (int o = 1; o <= 4; o <<= 1) {      // fixed-order tree over 8 chunks
        A.x += __shfl_xor(A.x, o, 64); A.y += __shfl_xor(A.y, o, 64);
        A.z += __shfl_xor(A.z, o, 64); A.w += __shfl_xor(A.w, o, 64);
        P.x += __shfl_xor(P.x, o, 64); P.y += __shfl_xor(P.y, o, 64);
        P.z += __shfl_xor(P.z, o, 64); P.w += __shfl_xor(P.w, o, 64);
    }
    if (c == 0) { bce[bb] = A; bpt[bb] = P; }
    __syncthreads();

    if (t == 0) {
        float dn[B_];
        for (int i = 0; i < B_; ++i) dn[i] = den[i];

        float mse = 0.f;
        float num_sp = 0.f, den_sp = 0.f, num_ds = 0.f, den_ds = 0.f;
        float num_nd = 0.f, den_nd = 0.f;
        float p_sp = 0.f, p_ds = 0.f, p_nd = 0.f, cnt_nd = 0.f;
        for (int b = 0; b < B_; ++b) {
            int rank = 0;
            for (int j = 0; j < B_; ++j)
                rank += ((dn[j] < dn[b]) || (dn[j] == dn[b] && j < b)) ? 1 : 0;
            float sp  = (rank >= B_ / 2) ? 1.0f : 0.0f;
            float dsv = 1.0f - sp;
            float4 A2 = bce[b], P2 = bpt[b];
            mse += P2.w;
            num_sp += sp  * A2.x;  den_sp += sp  * A2.y;
            num_ds += dsv * A2.x;  den_ds += dsv * A2.y;
            num_nd += A2.z;        den_nd += A2.w;
            p_sp   += sp  * P2.x;  p_ds   += dsv * P2.x;
            p_nd   += P2.y;        cnt_nd += P2.z;
        }
        float loss_ce = num_sp / (den_sp + EPS_)
                      + num_ds / (den_ds + EPS_)
                      + num_nd / (den_nd + EPS_);
        float half_cnt = (float)(N_ * (B_ / 2));   // sp/ds point counts = 512
        float loss_points = p_sp / (half_cnt + EPS_)
                          + p_ds / (half_cnt + EPS_)
                          + p_nd / (cnt_nd + EPS_);
        out[0] = loss_ce;
        out[1] = loss_points;
        out[2] = mse / (float)(B_ * 256 * 256);
    }
}

extern "C" void kernel_launch(void* const* d_in, const int* in_sizes, int n_in,
                              void* d_out, int out_size, void* d_ws, size_t ws_size,
                              hipStream_t stream) {
    const float* pred_logits = (const float*)d_in[0];
    const float* pred_points = (const float*)d_in[1];
    const float* tgt_points  = (const float*)d_in[2];
    const float* split_map   = (const float*)d_in[3];
    const float* den         = (const float*)d_in[4];
    const float* prob        = (const float*)d_in[5];
    const float* prob_est    = (const float*)d_in[6];
    const int*   src_idx     = (const int*)d_in[7];
    const int*   labels      = (const int*)d_in[8];
    float* out = (float*)d_out;

    float4* part = (float4*)d_ws;   // 512 float4 = 8 KB

    main_kernel<<<256, 1024, 0, stream>>>(pred_logits, pred_points, tgt_points,
                                          split_map, src_idx, labels,
                                          (const float4*)prob,
                                          (const float4*)prob_est, part);
    final_kernel<<<1, 64, 0, stream>>>(den, part, out);
}